// Round 8
// baseline (99.563 us; speedup 1.0000x reference)
//
#include <hip/hip_runtime.h>
#include <hip/hip_bf16.h>

#define BDIM 256
#define NPTS (8 * 2048)           // B*N
#define CC 128
#define DD 32
#define FF 512
#define NN 2048
#define SCALE 0.08838834764831845f   // 1/sqrt(128)

typedef float f32x4 __attribute__((ext_vector_type(4)));
typedef short s16x8 __attribute__((ext_vector_type(8)));
typedef unsigned short ushort_t;

__device__ __forceinline__ ushort_t bf16r(float x) {
    __hip_bfloat16 h = __float2bfloat16(x);
    return *reinterpret_cast<ushort_t*>(&h);
}
__device__ __forceinline__ float bf16tof(ushort_t u) {
    unsigned v = ((unsigned)u) << 16;
    return *reinterpret_cast<float*>(&v);
}
__device__ __forceinline__ unsigned pack2(float a, float b) {
    return ((unsigned)bf16r(b) << 16) | (unsigned)bf16r(a);
}

// ---------------- kernel 0: all weights f32 -> bf16, one launch ----------------
// dst layout (halves): W1b[65536] | W2b[65536] | Wq[4096] | Wk[4096] | Wv[16384] | Wt[16384]
__global__ void k_cvt_all(const float* __restrict__ W1, const float* __restrict__ W2,
                          const float* __restrict__ Wq, const float* __restrict__ Wk,
                          const float* __restrict__ Wv, const float* __restrict__ Wt,
                          ushort_t* __restrict__ dst) {
    int i = blockIdx.x * BDIM + threadIdx.x;     // float4 index, 43008 total
    const float* src; int off;
    if (i < 16384)      { src = W1; off = 0; }
    else if (i < 32768) { src = W2; off = 16384; }
    else if (i < 33792) { src = Wq; off = 32768; }
    else if (i < 34816) { src = Wk; off = 33792; }
    else if (i < 38912) { src = Wv; off = 34816; }
    else                { src = Wt; off = 38912; }
    float4 v = ((const float4*)src)[i - off];
    *(uint2*)(dst + (long)i * 4) = make_uint2(pack2(v.x, v.y), pack2(v.z, v.w));
}

// ---------------- kernel 1: MFMA q/k/vT projection ----------------
__global__ __launch_bounds__(256) void k_proj(
        const float* __restrict__ x, const ushort_t* __restrict__ Wb,
        const float* __restrict__ bv,
        ushort_t* __restrict__ qg, ushort_t* __restrict__ kg,
        ushort_t* __restrict__ vTg) {
    __shared__ ushort_t xs[32][136];
    __shared__ ushort_t qks[32][72];    // q cols 0-31, k cols 32-63
    __shared__ ushort_t vs[32][136];
    long base = (long)blockIdx.x * 32;
    int b = (int)(base >> 11);
    int n0 = (int)(base & (NN - 1));
    int t = threadIdx.x, w = t >> 6, l = t & 63, a = l & 15, g = l >> 4;
    {
        const float4* xg4 = (const float4*)(x + base * CC);
        #pragma unroll
        for (int rep = 0; rep < 4; ++rep) {
            int i = rep * BDIM + t;
            float4 v4 = xg4[i];
            int p = i >> 5, c4 = (i & 31) * 4;
            *(uint2*)&xs[p][c4] = make_uint2(pack2(v4.x, v4.y), pack2(v4.z, v4.w));
        }
    }
    s16x8 bF[3][4];
    #pragma unroll
    for (int ct = 0; ct < 3; ++ct) {
        int ctg = w * 3 + ct;
        #pragma unroll
        for (int ki = 0; ki < 4; ++ki)
            bF[ct][ki] = *(const s16x8*)(Wb + ((long)(ctg * 16 + a)) * CC + ki * 32 + g * 8);
    }
    __syncthreads();
    #pragma unroll
    for (int rt = 0; rt < 2; ++rt) {
        s16x8 aF[4];
        #pragma unroll
        for (int ki = 0; ki < 4; ++ki)
            aF[ki] = *(const s16x8*)&xs[rt * 16 + a][ki * 32 + g * 8];
        #pragma unroll
        for (int ct = 0; ct < 3; ++ct) {
            f32x4 acc = (f32x4){0.f, 0.f, 0.f, 0.f};
            #pragma unroll
            for (int ki = 0; ki < 4; ++ki)
                acc = __builtin_amdgcn_mfma_f32_16x16x32_bf16(aF[ki], bF[ct][ki], acc, 0, 0, 0);
            int ctg = w * 3 + ct;
            int oc = ctg * 16 + a;
            float bias = (oc >= 64) ? bv[oc - 64] : 0.f;
            #pragma unroll
            for (int r = 0; r < 4; ++r) {
                int p = rt * 16 + g * 4 + r;
                float val = acc[r] + bias;
                if (oc < 64) qks[p][oc] = bf16r(val);
                else         vs[p][oc - 64] = bf16r(val);
            }
        }
    }
    __syncthreads();
    {
        int p = t >> 3, c = (t & 7) * 4;
        *(uint2*)(qg + (base + p) * DD + c) = *(const uint2*)&qks[p][c];
        *(uint2*)(kg + (base + p) * DD + c) = *(const uint2*)&qks[p][32 + c];
    }
    #pragma unroll
    for (int rep = 0; rep < 2; ++rep) {
        int i = rep * BDIM + t;
        int c = i & 127, nch = i >> 7;
        int p0 = nch * 8;
        uint4 r;
        r.x = (unsigned)vs[p0+0][c] | ((unsigned)vs[p0+1][c] << 16);
        r.y = (unsigned)vs[p0+2][c] | ((unsigned)vs[p0+3][c] << 16);
        r.z = (unsigned)vs[p0+4][c] | ((unsigned)vs[p0+5][c] << 16);
        r.w = (unsigned)vs[p0+6][c] | ((unsigned)vs[p0+7][c] << 16);
        *(uint4*)(vTg + ((long)(b * CC + c)) * NN + n0 + p0) = r;
    }
}

// ---------------- kernel 2: MFMA row softmax sums (no max pass; |e|<~1.2 safe) ----------------
__global__ __launch_bounds__(256) void k_rowstats(
        const ushort_t* __restrict__ qg, const ushort_t* __restrict__ kg,
        float* __restrict__ rowinv) {
    __shared__ float ps[4][32];
    int b = blockIdx.x >> 6;
    int nt = (blockIdx.x & 63) * 32;
    int t = threadIdx.x, w = t >> 6, l = t & 63, a = l & 15, g = l >> 4;
    s16x8 qA[2];
    #pragma unroll
    for (int s = 0; s < 2; ++s)
        qA[s] = *(const s16x8*)(qg + ((long)(b * NN + nt + s*16 + a)) * DD + g*8);
    float sm[8];
    #pragma unroll
    for (int i = 0; i < 8; ++i) sm[i] = 0.f;
    for (int it = 0; it < 32; ++it) {
        int m0 = (it * 4 + w) * 16;
        s16x8 kB = *(const s16x8*)(kg + ((long)(b * NN + m0 + a)) * DD + g*8);
        #pragma unroll
        for (int s = 0; s < 2; ++s) {
            f32x4 D = (f32x4){0.f, 0.f, 0.f, 0.f};
            D = __builtin_amdgcn_mfma_f32_16x16x32_bf16(qA[s], kB, D, 0, 0, 0);
            #pragma unroll
            for (int r = 0; r < 4; ++r)
                sm[s * 4 + r] += __expf(D[r] * SCALE);
        }
    }
    #pragma unroll
    for (int off = 1; off < 16; off <<= 1)
        #pragma unroll
        for (int ix = 0; ix < 8; ++ix)
            sm[ix] += __shfl_xor(sm[ix], off, 64);
    if (a == 0) {
        #pragma unroll
        for (int s = 0; s < 2; ++s)
            #pragma unroll
            for (int r = 0; r < 4; ++r)
                ps[w][s * 16 + g * 4 + r] = sm[s * 4 + r];
    }
    __syncthreads();
    if (t < 32) {
        float S = ps[0][t] + ps[1][t] + ps[2][t] + ps[3][t];
        rowinv[(long)b * NN + nt + t] = 1.f / S;
    }
}

// ---------------- kernel 3: MFMA PV, 8 waves, reg-staged double buffer ----------------
__global__ __launch_bounds__(512) void k_pv(
        const ushort_t* __restrict__ qg, const ushort_t* __restrict__ kg,
        const ushort_t* __restrict__ vTg, const float* __restrict__ rowinv,
        float* __restrict__ xr) {
    __shared__ ushort_t qs[2][64][40];
    __shared__ ushort_t ks[32][40];
    __shared__ ushort_t vTs[2][128][72];
    __shared__ ushort_t pT[32][72];
    __shared__ float rin_s[2][64];
    int b = blockIdx.x >> 6;
    int m0 = (blockIdx.x & 63) * 32;
    int t = threadIdx.x, w = t >> 6, l = t & 63, a = l & 15, g = l >> 4;
    int nsub = w & 3, msub = w >> 2;
    const ushort_t* vTb = vTg + (long)b * CC * NN;
    if (t < 128) {
        int r = t >> 2, o = (t & 3) * 8;
        *(s16x8*)&ks[r][o] = *(const s16x8*)(kg + ((long)(b * NN + m0 + r)) * DD + o);
    }
    int qr = t >> 2, qo = (t & 3) * 8;
    int c0 = t >> 3, vo0 = (t & 7) * 8;
    int c1 = (512 + t) >> 3, vo1 = (t & 7) * 8;
    uint4 qreg = make_uint4(0, 0, 0, 0), vreg0, vreg1;
    float rinreg = 0.f;
    if (t < 256) qreg = *(const uint4*)(qg + ((long)(b * NN + qr)) * DD + qo);
    vreg0 = *(const uint4*)(vTb + (long)c0 * NN + vo0);
    vreg1 = *(const uint4*)(vTb + (long)c1 * NN + vo1);
    if (t < 64) rinreg = rowinv[(long)b * NN + t];
    if (t < 256) *(uint4*)&qs[0][qr][qo] = qreg;
    *(uint4*)&vTs[0][c0][vo0] = vreg0;
    *(uint4*)&vTs[0][c1][vo1] = vreg1;
    if (t < 64) rin_s[0][t] = rinreg;

    f32x4 acc[2];
    acc[0] = (f32x4){0.f, 0.f, 0.f, 0.f};
    acc[1] = (f32x4){0.f, 0.f, 0.f, 0.f};
    int cur = 0;
    for (int it = 0; it < 32; ++it) {
        __syncthreads();
        int ntn = (it + 1) * 64;
        if (it < 31) {
            if (t < 256) qreg = *(const uint4*)(qg + ((long)(b * NN + ntn + qr)) * DD + qo);
            vreg0 = *(const uint4*)(vTb + (long)c0 * NN + ntn + vo0);
            vreg1 = *(const uint4*)(vTb + (long)c1 * NN + ntn + vo1);
            if (t < 64) rinreg = rowinv[(long)b * NN + ntn + t];
        }
        s16x8 qf = *(const s16x8*)&qs[cur][nsub * 16 + a][g * 8];
        s16x8 kf = *(const s16x8*)&ks[msub * 16 + a][g * 8];
        f32x4 e = (f32x4){0.f, 0.f, 0.f, 0.f};
        e = __builtin_amdgcn_mfma_f32_16x16x32_bf16(qf, kf, e, 0, 0, 0);
        float p[4];
        #pragma unroll
        for (int r = 0; r < 4; ++r)
            p[r] = __expf(e[r] * SCALE) * rin_s[cur][nsub * 16 + g * 4 + r];
        *(uint2*)&pT[msub * 16 + a][nsub * 16 + g * 4] =
            make_uint2(pack2(p[0], p[1]), pack2(p[2], p[3]));
        __syncthreads();
        #pragma unroll
        for (int k2 = 0; k2 < 2; ++k2) {
            s16x8 A0 = *(const s16x8*)&pT[a][k2 * 32 + g * 8];
            s16x8 A1 = *(const s16x8*)&pT[16 + a][k2 * 32 + g * 8];
            s16x8 Bf = *(const s16x8*)&vTs[cur][w * 16 + a][k2 * 32 + g * 8];
            acc[0] = __builtin_amdgcn_mfma_f32_16x16x32_bf16(A0, Bf, acc[0], 0, 0, 0);
            acc[1] = __builtin_amdgcn_mfma_f32_16x16x32_bf16(A1, Bf, acc[1], 0, 0, 0);
        }
        if (it < 31) {
            if (t < 256) *(uint4*)&qs[cur ^ 1][qr][qo] = qreg;
            *(uint4*)&vTs[cur ^ 1][c0][vo0] = vreg0;
            *(uint4*)&vTs[cur ^ 1][c1][vo1] = vreg1;
            if (t < 64) rin_s[cur ^ 1][t] = rinreg;
        }
        cur ^= 1;
    }
    #pragma unroll
    for (int ms = 0; ms < 2; ++ms)
        #pragma unroll
        for (int r = 0; r < 4; ++r) {
            int m = m0 + ms * 16 + g * 4 + r;
            xr[((long)b * NN + m) * CC + w * 16 + a] = acc[ms][r];
        }
}

// ---------------- kernel 4: fused tproj + FF ----------------
// out = BN2(h + W2 relu(W1 h + bf1) + bf2), h = x + relu(BN1(Wt (x - xr) + bt))
// 32 points/block, 512 blocks, 4 waves. Weights read direct global->VGPR (L2-resident).
__global__ __launch_bounds__(256) void k_tff(
        const float* __restrict__ x, const float* __restrict__ xr,
        const ushort_t* __restrict__ Wtb, const float* __restrict__ bt,
        const float* __restrict__ g1, const float* __restrict__ b1,
        const float* __restrict__ m1, const float* __restrict__ v1,
        const ushort_t* __restrict__ W1b, const ushort_t* __restrict__ W2b,
        const float* __restrict__ bf1, const float* __restrict__ bf2,
        const float* __restrict__ g2, const float* __restrict__ b2,
        const float* __restrict__ m2, const float* __restrict__ v2,
        float* __restrict__ out) {
    __shared__ ushort_t ds[32][136];     // bf16(x - xr)
    __shared__ ushort_t hs[32][136];     // bf16 h
    __shared__ ushort_t fss[32][520];    // fs (relu f32->bf16), stride 520: 2-way banks
    long base = (long)blockIdx.x * 32;
    int t = threadIdx.x, l = t & 63, wid = t >> 6;
    int ph = wid & 1, fh = wid >> 1;
    int lr = l & 15, lg = l >> 4;
    // stage d = x - xr (bf16); keep x in f32 regs? x needed only via h (residual uses h).
    {
        const float4* xg4 = (const float4*)(x + base * CC);
        const float4* rg4 = (const float4*)(xr + base * CC);
        #pragma unroll
        for (int rep = 0; rep < 4; ++rep) {
            int i = rep * BDIM + t;
            float4 xv = xg4[i], rv = rg4[i];
            int p = i >> 5, c4 = (i & 31) * 4;
            *(uint2*)&ds[p][c4] = make_uint2(pack2(xv.x - rv.x, xv.y - rv.y),
                                             pack2(xv.z - rv.z, xv.w - rv.w));
            *(uint2*)&hs[p][c4] = make_uint2(pack2(xv.x, xv.y), pack2(xv.z, xv.w));  // x for now
        }
    }
    __syncthreads();
    // ---- tproj: h = x + relu(BN1(Wt d + bt)); wave (ph,fh) -> o-range fh*64 + oi*16 ----
    {
        s16x8 aF[4];
        #pragma unroll
        for (int ki = 0; ki < 4; ++ki)
            aF[ki] = *(const s16x8*)&ds[ph * 16 + lr][ki * 32 + lg * 8];
        #pragma unroll
        for (int oi = 0; oi < 4; ++oi) {
            int ot = fh * 4 + oi;
            f32x4 acc = (f32x4){0.f, 0.f, 0.f, 0.f};
            #pragma unroll
            for (int ki = 0; ki < 4; ++ki) {
                s16x8 bF = *(const s16x8*)(Wtb + ((long)(ot * 16 + lr)) * CC + ki * 32 + lg * 8);
                acc = __builtin_amdgcn_mfma_f32_16x16x32_bf16(aF[ki], bF, acc, 0, 0, 0);
            }
            int o = ot * 16 + lr;
            float sc = g1[o] * rsqrtf(v1[o] + 1e-5f);
            float mm = m1[o], bb = b1[o], bo = bt[o];
            #pragma unroll
            for (int r = 0; r < 4; ++r) {
                int p = ph * 16 + lg * 4 + r;
                float tv = ((acc[r] + bo) - mm) * sc + bb;
                tv = fmaxf(tv, 0.f);
                hs[p][o] = bf16r(bf16tof(hs[p][o]) + tv);   // h = x + relu(...)
            }
        }
    }
    __syncthreads();
    // ---- FF phase 1: fs = relu(W1 h + bf1); wave (ph,fh) -> f-range fh*256, 16 ft tiles ----
    {
        s16x8 hA[4];
        #pragma unroll
        for (int ki = 0; ki < 4; ++ki)
            hA[ki] = *(const s16x8*)&hs[ph * 16 + lr][ki * 32 + lg * 8];
        #pragma unroll
        for (int ft = 0; ft < 16; ++ft) {
            int f = fh * 256 + ft * 16 + lr;
            f32x4 a1 = (f32x4){0.f, 0.f, 0.f, 0.f};
            #pragma unroll
            for (int ki = 0; ki < 4; ++ki) {
                s16x8 bfr = *(const s16x8*)(W1b + (long)f * CC + ki * 32 + lg * 8);
                a1 = __builtin_amdgcn_mfma_f32_16x16x32_bf16(hA[ki], bfr, a1, 0, 0, 0);
            }
            float bias = bf1[f];
            #pragma unroll
            for (int r = 0; r < 4; ++r) {
                float vv = fmaxf(a1[r] + bias, 0.f);
                fss[ph * 16 + lg * 4 + r][f] = bf16r(vv);
            }
        }
    }
    __syncthreads();
    // ---- FF phase 2: out = BN2(h + W2 fs + bf2); wave (ph,fh) -> o-range fh*64 ----
    {
        f32x4 acc2[4];
        #pragma unroll
        for (int i = 0; i < 4; ++i) acc2[i] = (f32x4){0.f, 0.f, 0.f, 0.f};
        #pragma unroll
        for (int k2 = 0; k2 < 16; ++k2) {
            s16x8 afr = *(const s16x8*)&fss[ph * 16 + lr][k2 * 32 + lg * 8];
            #pragma unroll
            for (int oi = 0; oi < 4; ++oi) {
                int ot = fh * 4 + oi;
                s16x8 bfr = *(const s16x8*)(W2b + ((long)(ot * 16 + lr)) * FF + k2 * 32 + lg * 8);
                acc2[oi] = __builtin_amdgcn_mfma_f32_16x16x32_bf16(afr, bfr, acc2[oi], 0, 0, 0);
            }
        }
        #pragma unroll
        for (int oi = 0; oi < 4; ++oi) {
            int o = (fh * 4 + oi) * 16 + lr;
            float sc = g2[o] * rsqrtf(v2[o] + 1e-5f);
            float mm = m2[o], bb = b2[o], bias2 = bf2[o];
            #pragma unroll
            for (int r = 0; r < 4; ++r) {
                int p = ph * 16 + lg * 4 + r;
                float val = bf16tof(hs[p][o]) + acc2[oi][r] + bias2;
                out[(base + p) * CC + o] = (val - mm) * sc + bb;
            }
        }
    }
}

extern "C" void kernel_launch(void* const* d_in, const int* in_sizes, int n_in,
                              void* d_out, int out_size, void* d_ws, size_t ws_size,
                              hipStream_t stream) {
    const float* x   = (const float*)d_in[0];
    const float* Wq  = (const float*)d_in[1];
    const float* Wk  = (const float*)d_in[2];
    const float* Wv  = (const float*)d_in[3];
    const float* bv  = (const float*)d_in[4];
    const float* Wt  = (const float*)d_in[5];
    const float* bt  = (const float*)d_in[6];
    const float* g1  = (const float*)d_in[7];
    const float* b1  = (const float*)d_in[8];
    const float* m1  = (const float*)d_in[9];
    const float* v1  = (const float*)d_in[10];
    const float* W1  = (const float*)d_in[11];
    const float* bf1 = (const float*)d_in[12];
    const float* W2  = (const float*)d_in[13];
    const float* bf2 = (const float*)d_in[14];
    const float* g2  = (const float*)d_in[15];
    const float* b2  = (const float*)d_in[16];
    const float* m2  = (const float*)d_in[17];
    const float* v2  = (const float*)d_in[18];
    float* out = (float*)d_out;

    float* ws  = (float*)d_ws;
    float* xr  = ws;                            // NPTS*CC f32
    float* rin = xr + (long)NPTS * CC;          // NPTS
    ushort_t* qg   = (ushort_t*)(rin + NPTS);   // NPTS*DD
    ushort_t* kg   = qg + (long)NPTS * DD;      // NPTS*DD
    ushort_t* vTg  = kg + (long)NPTS * DD;      // NPTS*CC ([b][c][n])
    ushort_t* W1b  = vTg + (long)NPTS * CC;     // FF*CC
    ushort_t* W2b  = W1b + FF * CC;             // FF*CC
    ushort_t* Wb   = W2b + FF * CC;             // 192*CC (Wq|Wk|Wv)
    ushort_t* Wtb  = Wb + 192 * CC;             // CC*CC

    k_cvt_all<<<168, BDIM, 0, stream>>>(W1, W2, Wq, Wk, Wv, Wt, W1b);
    k_proj<<<NPTS / 32, BDIM, 0, stream>>>(x, Wb, bv, qg, kg, vTg);
    k_rowstats<<<8 * (NN / 32), BDIM, 0, stream>>>(qg, kg, rin);
    k_pv<<<8 * (NN / 32), 512, 0, stream>>>(qg, kg, vTg, rin, xr);
    k_tff<<<NPTS / 32, BDIM, 0, stream>>>(x, xr, Wtb, bt, g1, b1, m1, v1,
                                          W1b, W2b, bf1, bf2, g2, b2, m2, v2, out);
}

// Round 9
// 81.702 us; speedup vs baseline: 1.2186x; 1.2186x over previous
//
#include <hip/hip_runtime.h>
#include <hip/hip_bf16.h>

#define BDIM 256
#define NPTS (8 * 2048)           // B*N
#define CC 128
#define DD 32
#define FF 512
#define NN 2048
#define SCALE 0.08838834764831845f   // 1/sqrt(128)

typedef float f32x4 __attribute__((ext_vector_type(4)));
typedef short s16x8 __attribute__((ext_vector_type(8)));
typedef unsigned short ushort_t;

__device__ __forceinline__ ushort_t bf16r(float x) {
    __hip_bfloat16 h = __float2bfloat16(x);
    return *reinterpret_cast<ushort_t*>(&h);
}
__device__ __forceinline__ float bf16tof(ushort_t u) {
    unsigned v = ((unsigned)u) << 16;
    return *reinterpret_cast<float*>(&v);
}
__device__ __forceinline__ unsigned pack2(float a, float b) {
    return ((unsigned)bf16r(b) << 16) | (unsigned)bf16r(a);
}

// ---------------- kernel 0: all weights f32 -> bf16, one launch ----------------
// dst layout (halves): W1b[65536] | W2b[65536] | Wq[4096] | Wk[4096] | Wv[16384] | Wt[16384]
__global__ void k_cvt_all(const float* __restrict__ W1, const float* __restrict__ W2,
                          const float* __restrict__ Wq, const float* __restrict__ Wk,
                          const float* __restrict__ Wv, const float* __restrict__ Wt,
                          ushort_t* __restrict__ dst) {
    int i = blockIdx.x * BDIM + threadIdx.x;     // float4 index, 43008 total
    const float* src; int off;
    if (i < 16384)      { src = W1; off = 0; }
    else if (i < 32768) { src = W2; off = 16384; }
    else if (i < 33792) { src = Wq; off = 32768; }
    else if (i < 34816) { src = Wk; off = 33792; }
    else if (i < 38912) { src = Wv; off = 34816; }
    else                { src = Wt; off = 38912; }
    float4 v = ((const float4*)src)[i - off];
    *(uint2*)(dst + (long)i * 4) = make_uint2(pack2(v.x, v.y), pack2(v.z, v.w));
}

// ---------------- kernel 1: MFMA q/k/vT projection ----------------
__global__ __launch_bounds__(256) void k_proj(
        const float* __restrict__ x, const ushort_t* __restrict__ Wb,
        const float* __restrict__ bv,
        ushort_t* __restrict__ qg, ushort_t* __restrict__ kg,
        ushort_t* __restrict__ vTg) {
    __shared__ ushort_t xs[32][136];
    __shared__ ushort_t qks[32][72];    // q cols 0-31, k cols 32-63
    __shared__ ushort_t vs[32][136];
    long base = (long)blockIdx.x * 32;
    int b = (int)(base >> 11);
    int n0 = (int)(base & (NN - 1));
    int t = threadIdx.x, w = t >> 6, l = t & 63, a = l & 15, g = l >> 4;
    {
        const float4* xg4 = (const float4*)(x + base * CC);
        #pragma unroll
        for (int rep = 0; rep < 4; ++rep) {
            int i = rep * BDIM + t;
            float4 v4 = xg4[i];
            int p = i >> 5, c4 = (i & 31) * 4;
            *(uint2*)&xs[p][c4] = make_uint2(pack2(v4.x, v4.y), pack2(v4.z, v4.w));
        }
    }
    s16x8 bF[3][4];
    #pragma unroll
    for (int ct = 0; ct < 3; ++ct) {
        int ctg = w * 3 + ct;
        #pragma unroll
        for (int ki = 0; ki < 4; ++ki)
            bF[ct][ki] = *(const s16x8*)(Wb + ((long)(ctg * 16 + a)) * CC + ki * 32 + g * 8);
    }
    __syncthreads();
    #pragma unroll
    for (int rt = 0; rt < 2; ++rt) {
        s16x8 aF[4];
        #pragma unroll
        for (int ki = 0; ki < 4; ++ki)
            aF[ki] = *(const s16x8*)&xs[rt * 16 + a][ki * 32 + g * 8];
        #pragma unroll
        for (int ct = 0; ct < 3; ++ct) {
            f32x4 acc = (f32x4){0.f, 0.f, 0.f, 0.f};
            #pragma unroll
            for (int ki = 0; ki < 4; ++ki)
                acc = __builtin_amdgcn_mfma_f32_16x16x32_bf16(aF[ki], bF[ct][ki], acc, 0, 0, 0);
            int ctg = w * 3 + ct;
            int oc = ctg * 16 + a;
            float bias = (oc >= 64) ? bv[oc - 64] : 0.f;
            #pragma unroll
            for (int r = 0; r < 4; ++r) {
                int p = rt * 16 + g * 4 + r;
                float val = acc[r] + bias;
                if (oc < 64) qks[p][oc] = bf16r(val);
                else         vs[p][oc - 64] = bf16r(val);
            }
        }
    }
    __syncthreads();
    {
        int p = t >> 3, c = (t & 7) * 4;
        *(uint2*)(qg + (base + p) * DD + c) = *(const uint2*)&qks[p][c];
        *(uint2*)(kg + (base + p) * DD + c) = *(const uint2*)&qks[p][32 + c];
    }
    #pragma unroll
    for (int rep = 0; rep < 2; ++rep) {
        int i = rep * BDIM + t;
        int c = i & 127, nch = i >> 7;
        int p0 = nch * 8;
        uint4 r;
        r.x = (unsigned)vs[p0+0][c] | ((unsigned)vs[p0+1][c] << 16);
        r.y = (unsigned)vs[p0+2][c] | ((unsigned)vs[p0+3][c] << 16);
        r.z = (unsigned)vs[p0+4][c] | ((unsigned)vs[p0+5][c] << 16);
        r.w = (unsigned)vs[p0+6][c] | ((unsigned)vs[p0+7][c] << 16);
        *(uint4*)(vTg + ((long)(b * CC + c)) * NN + n0 + p0) = r;
    }
}

// ---------------- kernel 2: MFMA row softmax sums, 64 rows/block + kB prefetch ----------------
// grid: 8 b x 32 n-tiles(64) = 256 blocks.
__global__ __launch_bounds__(256) void k_rowstats(
        const ushort_t* __restrict__ qg, const ushort_t* __restrict__ kg,
        float* __restrict__ rowinv) {
    __shared__ float ps[4][64];
    int b = blockIdx.x >> 5;
    int nt = (blockIdx.x & 31) * 64;
    int t = threadIdx.x, w = t >> 6, l = t & 63, a = l & 15, g = l >> 4;
    s16x8 qA[4];
    #pragma unroll
    for (int s = 0; s < 4; ++s)
        qA[s] = *(const s16x8*)(qg + ((long)(b * NN + nt + s*16 + a)) * DD + g*8);
    float sm[16];
    #pragma unroll
    for (int i = 0; i < 16; ++i) sm[i] = 0.f;
    s16x8 kB = *(const s16x8*)(kg + ((long)(b * NN + w * 16 + a)) * DD + g*8);
    for (int it = 0; it < 32; ++it) {
        s16x8 kBn;
        if (it < 31)
            kBn = *(const s16x8*)(kg + ((long)(b * NN + ((it+1)*4 + w)*16 + a)) * DD + g*8);
        #pragma unroll
        for (int s = 0; s < 4; ++s) {
            f32x4 D = (f32x4){0.f, 0.f, 0.f, 0.f};
            D = __builtin_amdgcn_mfma_f32_16x16x32_bf16(qA[s], kB, D, 0, 0, 0);
            #pragma unroll
            for (int r = 0; r < 4; ++r)
                sm[s * 4 + r] += __expf(D[r] * SCALE);
        }
        kB = kBn;
    }
    #pragma unroll
    for (int off = 1; off < 16; off <<= 1)
        #pragma unroll
        for (int ix = 0; ix < 16; ++ix)
            sm[ix] += __shfl_xor(sm[ix], off, 64);
    if (a == 0) {
        #pragma unroll
        for (int s = 0; s < 4; ++s)
            #pragma unroll
            for (int r = 0; r < 4; ++r)
                ps[w][s * 16 + g * 4 + r] = sm[s * 4 + r];
    }
    __syncthreads();
    if (t < 64) {
        float S = ps[0][t] + ps[1][t] + ps[2][t] + ps[3][t];
        rowinv[(long)b * NN + nt + t] = 1.f / S;
    }
}

// ---------------- kernel 3: MFMA PV, 8 waves, reg-staged double buffer ----------------
__global__ __launch_bounds__(512) void k_pv(
        const ushort_t* __restrict__ qg, const ushort_t* __restrict__ kg,
        const ushort_t* __restrict__ vTg, const float* __restrict__ rowinv,
        float* __restrict__ xr) {
    __shared__ ushort_t qs[2][64][40];
    __shared__ ushort_t ks[32][40];
    __shared__ ushort_t vTs[2][128][72];
    __shared__ ushort_t pT[32][72];
    __shared__ float rin_s[2][64];
    int b = blockIdx.x >> 6;
    int m0 = (blockIdx.x & 63) * 32;
    int t = threadIdx.x, w = t >> 6, l = t & 63, a = l & 15, g = l >> 4;
    int nsub = w & 3, msub = w >> 2;
    const ushort_t* vTb = vTg + (long)b * CC * NN;
    if (t < 128) {
        int r = t >> 2, o = (t & 3) * 8;
        *(s16x8*)&ks[r][o] = *(const s16x8*)(kg + ((long)(b * NN + m0 + r)) * DD + o);
    }
    int qr = t >> 2, qo = (t & 3) * 8;
    int c0 = t >> 3, vo0 = (t & 7) * 8;
    int c1 = (512 + t) >> 3, vo1 = (t & 7) * 8;
    uint4 qreg = make_uint4(0, 0, 0, 0), vreg0, vreg1;
    float rinreg = 0.f;
    if (t < 256) qreg = *(const uint4*)(qg + ((long)(b * NN + qr)) * DD + qo);
    vreg0 = *(const uint4*)(vTb + (long)c0 * NN + vo0);
    vreg1 = *(const uint4*)(vTb + (long)c1 * NN + vo1);
    if (t < 64) rinreg = rowinv[(long)b * NN + t];
    if (t < 256) *(uint4*)&qs[0][qr][qo] = qreg;
    *(uint4*)&vTs[0][c0][vo0] = vreg0;
    *(uint4*)&vTs[0][c1][vo1] = vreg1;
    if (t < 64) rin_s[0][t] = rinreg;

    f32x4 acc[2];
    acc[0] = (f32x4){0.f, 0.f, 0.f, 0.f};
    acc[1] = (f32x4){0.f, 0.f, 0.f, 0.f};
    int cur = 0;
    for (int it = 0; it < 32; ++it) {
        __syncthreads();
        int ntn = (it + 1) * 64;
        if (it < 31) {
            if (t < 256) qreg = *(const uint4*)(qg + ((long)(b * NN + ntn + qr)) * DD + qo);
            vreg0 = *(const uint4*)(vTb + (long)c0 * NN + ntn + vo0);
            vreg1 = *(const uint4*)(vTb + (long)c1 * NN + ntn + vo1);
            if (t < 64) rinreg = rowinv[(long)b * NN + ntn + t];
        }
        s16x8 qf = *(const s16x8*)&qs[cur][nsub * 16 + a][g * 8];
        s16x8 kf = *(const s16x8*)&ks[msub * 16 + a][g * 8];
        f32x4 e = (f32x4){0.f, 0.f, 0.f, 0.f};
        e = __builtin_amdgcn_mfma_f32_16x16x32_bf16(qf, kf, e, 0, 0, 0);
        float p[4];
        #pragma unroll
        for (int r = 0; r < 4; ++r)
            p[r] = __expf(e[r] * SCALE) * rin_s[cur][nsub * 16 + g * 4 + r];
        *(uint2*)&pT[msub * 16 + a][nsub * 16 + g * 4] =
            make_uint2(pack2(p[0], p[1]), pack2(p[2], p[3]));
        __syncthreads();
        #pragma unroll
        for (int k2 = 0; k2 < 2; ++k2) {
            s16x8 A0 = *(const s16x8*)&pT[a][k2 * 32 + g * 8];
            s16x8 A1 = *(const s16x8*)&pT[16 + a][k2 * 32 + g * 8];
            s16x8 Bf = *(const s16x8*)&vTs[cur][w * 16 + a][k2 * 32 + g * 8];
            acc[0] = __builtin_amdgcn_mfma_f32_16x16x32_bf16(A0, Bf, acc[0], 0, 0, 0);
            acc[1] = __builtin_amdgcn_mfma_f32_16x16x32_bf16(A1, Bf, acc[1], 0, 0, 0);
        }
        if (it < 31) {
            if (t < 256) *(uint4*)&qs[cur ^ 1][qr][qo] = qreg;
            *(uint4*)&vTs[cur ^ 1][c0][vo0] = vreg0;
            *(uint4*)&vTs[cur ^ 1][c1][vo1] = vreg1;
            if (t < 64) rin_s[cur ^ 1][t] = rinreg;
        }
        cur ^= 1;
    }
    #pragma unroll
    for (int ms = 0; ms < 2; ++ms)
        #pragma unroll
        for (int r = 0; r < 4; ++r) {
            int m = m0 + ms * 16 + g * 4 + r;
            xr[((long)b * NN + m) * CC + w * 16 + a] = acc[ms][r];
        }
}

// ---------------- kernel 4: MFMA t-projection (staged Wt) ----------------
__global__ __launch_bounds__(256) void k_tproj(
        const float* __restrict__ x, const float* __restrict__ xr,
        const ushort_t* __restrict__ Wtb, const float* __restrict__ bt,
        const float* __restrict__ g1, const float* __restrict__ b1,
        const float* __restrict__ m1, const float* __restrict__ v1,
        ushort_t* __restrict__ hb) {
    __shared__ ushort_t ds[32][136];
    __shared__ ushort_t xb[32][136];
    __shared__ ushort_t wt[128][136];
    long base = (long)blockIdx.x * 32;
    int t = threadIdx.x, l = t & 63, wid = t >> 6;
    int ph = wid & 1, fh = wid >> 1;
    int lr = l & 15, lg = l >> 4;
    {
        const float4* xg4 = (const float4*)(x + base * CC);
        const float4* rg4 = (const float4*)(xr + base * CC);
        #pragma unroll
        for (int rep = 0; rep < 4; ++rep) {
            int i = rep * BDIM + t;
            float4 xv = xg4[i], rv = rg4[i];
            int p = i >> 5, c4 = (i & 31) * 4;
            *(uint2*)&ds[p][c4] = make_uint2(pack2(xv.x - rv.x, xv.y - rv.y),
                                             pack2(xv.z - rv.z, xv.w - rv.w));
            *(uint2*)&xb[p][c4] = make_uint2(pack2(xv.x, xv.y), pack2(xv.z, xv.w));
        }
    }
    {
        #pragma unroll
        for (int rep = 0; rep < 8; ++rep) {
            int i = rep * BDIM + t;
            int r = i >> 4, cc0 = (i & 15) * 8;
            *(uint4*)&wt[r][cc0] = *(const uint4*)(Wtb + (long)r * CC + cc0);
        }
    }
    __syncthreads();
    s16x8 aF[4];
    #pragma unroll
    for (int ki = 0; ki < 4; ++ki)
        aF[ki] = *(const s16x8*)&ds[ph * 16 + lr][ki * 32 + lg * 8];
    #pragma unroll
    for (int oi = 0; oi < 4; ++oi) {
        int ot = fh * 4 + oi;
        f32x4 acc = (f32x4){0.f, 0.f, 0.f, 0.f};
        #pragma unroll
        for (int ki = 0; ki < 4; ++ki) {
            s16x8 bF = *(const s16x8*)&wt[ot * 16 + lr][ki * 32 + lg * 8];
            acc = __builtin_amdgcn_mfma_f32_16x16x32_bf16(aF[ki], bF, acc, 0, 0, 0);
        }
        int o = ot * 16 + lr;
        float sc = g1[o] * rsqrtf(v1[o] + 1e-5f);
        float mm = m1[o], bb = b1[o], bo = bt[o];
        #pragma unroll
        for (int r = 0; r < 4; ++r) {
            int p = ph * 16 + lg * 4 + r;
            float tv = ((acc[r] + bo) - mm) * sc + bb;
            tv = fmaxf(tv, 0.f);
            hb[(base + p) * CC + o] = bf16r(bf16tof(xb[p][o]) + tv);
        }
    }
}

// ---------------- kernel 5: MFMA fused FF, double-buffered weight chunks ----------------
// XOR-swizzled unpadded weight buffers: lds[row][col ^ ((row&7)*8)] (halves).
__global__ __launch_bounds__(256) void k_ff(
        const ushort_t* __restrict__ hb, const ushort_t* __restrict__ W1b,
        const ushort_t* __restrict__ W2b,
        const float* __restrict__ bf1, const float* __restrict__ bf2,
        const float* __restrict__ g2, const float* __restrict__ b2,
        const float* __restrict__ m2, const float* __restrict__ v2,
        float* __restrict__ out) {
    __shared__ ushort_t hs[32][136];
    __shared__ ushort_t w1s[2][64][128];
    __shared__ ushort_t w2s[2][128][64];
    __shared__ ushort_t fss[32][72];
    long pbase = (long)blockIdx.x * 32;
    int t = threadIdx.x;
    int l = t & 63, wid = t >> 6;
    int ph = wid & 1, fh = wid >> 1;
    int lr = l & 15, lg = l >> 4;
    // stage h tile
    for (int i = t; i < 512; i += BDIM) {
        int r = i >> 4, c0 = (i & 15) * 8;
        *(uint4*)&hs[r][c0] = *(const uint4*)(hb + (pbase + r) * CC + c0);
    }
    // stage chunk 0 (swizzled)
    #pragma unroll
    for (int rep = 0; rep < 4; ++rep) {
        int i = rep * BDIM + t;
        int r = i >> 4, c0 = (i & 15) * 8;
        *(uint4*)&w1s[0][r][c0 ^ ((r & 7) * 8)] = *(const uint4*)(W1b + (long)r * CC + c0);
    }
    #pragma unroll
    for (int rep = 0; rep < 4; ++rep) {
        int i = rep * BDIM + t;
        int r = i >> 3, c0 = (i & 7) * 8;
        *(uint4*)&w2s[0][r][c0 ^ ((r & 7) * 8)] = *(const uint4*)(W2b + (long)r * FF + c0);
    }
    __syncthreads();
    s16x8 hA[4];
    #pragma unroll
    for (int ki = 0; ki < 4; ++ki)
        hA[ki] = *(const s16x8*)&hs[ph * 16 + lr][ki * 32 + lg * 8];
    f32x4 acc2[4];
    #pragma unroll
    for (int i = 0; i < 4; ++i) acc2[i] = (f32x4){0.f, 0.f, 0.f, 0.f};

    int cur = 0;
    uint4 wrg0, wrg1, wrg2, wrg3, wrg4, wrg5, wrg6, wrg7;
    for (int fc = 0; fc < 8; ++fc) {
        if (fc) __syncthreads();    // (A) chunk[cur] visible; fss from prev consumed
        int f0 = fc * 64;
        if (fc < 7) {               // issue next-chunk loads (in flight across FF1+FF2)
            int f0n = f0 + 64;
            int r1 = t >> 4, c1 = (t & 15) * 8;
            int r2 = t >> 3, c2 = (t & 7) * 8;
            wrg0 = *(const uint4*)(W1b + (long)(f0n + r1) * CC + c1);
            wrg1 = *(const uint4*)(W1b + (long)(f0n + 16 + r1) * CC + c1);
            wrg2 = *(const uint4*)(W1b + (long)(f0n + 32 + r1) * CC + c1);
            wrg3 = *(const uint4*)(W1b + (long)(f0n + 48 + r1) * CC + c1);
            wrg4 = *(const uint4*)(W2b + (long)r2 * FF + f0n + c2);
            wrg5 = *(const uint4*)(W2b + (long)(32 + r2) * FF + f0n + c2);
            wrg6 = *(const uint4*)(W2b + (long)(64 + r2) * FF + f0n + c2);
            wrg7 = *(const uint4*)(W2b + (long)(96 + r2) * FF + f0n + c2);
        }
        // FF1: fs chunk = relu(h . W1^T + bf1)
        #pragma unroll
        for (int fi = 0; fi < 2; ++fi) {
            int ft = fh * 2 + fi;
            int row = ft * 16 + lr;
            f32x4 a1 = (f32x4){0.f, 0.f, 0.f, 0.f};
            #pragma unroll
            for (int ki = 0; ki < 4; ++ki) {
                int col = ki * 32 + lg * 8;
                s16x8 bfr = *(const s16x8*)&w1s[cur][row][col ^ ((row & 7) * 8)];
                a1 = __builtin_amdgcn_mfma_f32_16x16x32_bf16(hA[ki], bfr, a1, 0, 0, 0);
            }
            float bias = bf1[f0 + ft * 16 + lr];
            #pragma unroll
            for (int r = 0; r < 4; ++r) {
                float vv = fmaxf(a1[r] + bias, 0.f);
                fss[ph * 16 + lg * 4 + r][ft * 16 + lr] = bf16r(vv);
            }
        }
        __syncthreads();            // (B) fss ready
        // FF2: acc2 += fs . W2_chunk^T
        #pragma unroll
        for (int k2 = 0; k2 < 2; ++k2) {
            s16x8 afr = *(const s16x8*)&fss[ph * 16 + lr][k2 * 32 + lg * 8];
            #pragma unroll
            for (int oi = 0; oi < 4; ++oi) {
                int ot = fh * 4 + oi;
                int row = ot * 16 + lr;
                int col = k2 * 32 + lg * 8;
                s16x8 bfr = *(const s16x8*)&w2s[cur][row][col ^ ((row & 7) * 8)];
                acc2[oi] = __builtin_amdgcn_mfma_f32_16x16x32_bf16(afr, bfr, acc2[oi], 0, 0, 0);
            }
        }
        if (fc < 7) {               // write next chunk into other buffer
            int nb = cur ^ 1;
            int r1 = t >> 4, c1 = (t & 15) * 8;
            int r2 = t >> 3, c2 = (t & 7) * 8;
            *(uint4*)&w1s[nb][r1][c1 ^ ((r1 & 7) * 8)] = wrg0;
            *(uint4*)&w1s[nb][16 + r1][c1 ^ ((r1 & 7) * 8)] = wrg1;
            *(uint4*)&w1s[nb][32 + r1][c1 ^ ((r1 & 7) * 8)] = wrg2;
            *(uint4*)&w1s[nb][48 + r1][c1 ^ ((r1 & 7) * 8)] = wrg3;
            *(uint4*)&w2s[nb][r2][c2 ^ ((r2 & 7) * 8)] = wrg4;
            *(uint4*)&w2s[nb][32 + r2][c2 ^ (((32 + r2) & 7) * 8)] = wrg5;
            *(uint4*)&w2s[nb][64 + r2][c2 ^ (((64 + r2) & 7) * 8)] = wrg6;
            *(uint4*)&w2s[nb][96 + r2][c2 ^ (((96 + r2) & 7) * 8)] = wrg7;
            cur = nb;
        }
    }
    // epilogue
    #pragma unroll
    for (int oi = 0; oi < 4; ++oi) {
        int o = (fh * 4 + oi) * 16 + lr;
        float sc = g2[o] * rsqrtf(v2[o] + 1e-5f);
        float mm = m2[o], bb = b2[o], bias2 = bf2[o];
        #pragma unroll
        for (int r = 0; r < 4; ++r) {
            int p = ph * 16 + lg * 4 + r;
            float val = bf16tof(hs[p][o]) + acc2[oi][r] + bias2;
            out[(pbase + p) * CC + o] = (val - mm) * sc + bb;
        }
    }
}

extern "C" void kernel_launch(void* const* d_in, const int* in_sizes, int n_in,
                              void* d_out, int out_size, void* d_ws, size_t ws_size,
                              hipStream_t stream) {
    const float* x   = (const float*)d_in[0];
    const float* Wq  = (const float*)d_in[1];
    const float* Wk  = (const float*)d_in[2];
    const float* Wv  = (const float*)d_in[3];
    const float* bv  = (const float*)d_in[4];
    const float* Wt  = (const float*)d_in[5];
    const float* bt  = (const float*)d_in[6];
    const float* g1  = (const float*)d_in[7];
    const float* b1  = (const float*)d_in[8];
    const float* m1  = (const float*)d_in[9];
    const float* v1  = (const float*)d_in[10];
    const float* W1  = (const float*)d_in[11];
    const float* bf1 = (const float*)d_in[12];
    const float* W2  = (const float*)d_in[13];
    const float* bf2 = (const float*)d_in[14];
    const float* g2  = (const float*)d_in[15];
    const float* b2  = (const float*)d_in[16];
    const float* m2  = (const float*)d_in[17];
    const float* v2  = (const float*)d_in[18];
    float* out = (float*)d_out;

    float* ws  = (float*)d_ws;
    float* xr  = ws;                            // NPTS*CC f32
    float* rin = xr + (long)NPTS * CC;          // NPTS
    ushort_t* qg   = (ushort_t*)(rin + NPTS);   // NPTS*DD
    ushort_t* kg   = qg + (long)NPTS * DD;      // NPTS*DD
    ushort_t* vTg  = kg + (long)NPTS * DD;      // NPTS*CC ([b][c][n])
    ushort_t* hbuf = vTg + (long)NPTS * CC;     // NPTS*CC
    ushort_t* W1b  = hbuf + (long)NPTS * CC;    // FF*CC
    ushort_t* W2b  = W1b + FF * CC;             // FF*CC
    ushort_t* Wb   = W2b + FF * CC;             // 192*CC (Wq|Wk|Wv)
    ushort_t* Wtb  = Wb + 192 * CC;             // CC*CC

    k_cvt_all<<<168, BDIM, 0, stream>>>(W1, W2, Wq, Wk, Wv, Wt, W1b);
    k_proj<<<NPTS / 32, BDIM, 0, stream>>>(x, Wb, bv, qg, kg, vTg);
    k_rowstats<<<8 * (NN / 64), BDIM, 0, stream>>>(qg, kg, rin);
    k_pv<<<8 * (NN / 32), 512, 0, stream>>>(qg, kg, vTg, rin, xr);
    k_tproj<<<NPTS / 32, BDIM, 0, stream>>>(x, xr, Wtb, bt, g1, b1, m1, v1, hbuf);
    k_ff<<<NPTS / 32, BDIM, 0, stream>>>(hbuf, W1b, W2b, bf1, bf2, g2, b2, m2, v2, out);
}

// Round 10
// 80.617 us; speedup vs baseline: 1.2350x; 1.0135x over previous
//
#include <hip/hip_runtime.h>
#include <hip/hip_bf16.h>

#define BDIM 256
#define NPTS (8 * 2048)           // B*N
#define CC 128
#define DD 32
#define FF 512
#define NN 2048
#define SCALE 0.08838834764831845f   // 1/sqrt(128)

typedef float f32x4 __attribute__((ext_vector_type(4)));
typedef short s16x8 __attribute__((ext_vector_type(8)));
typedef unsigned short ushort_t;

__device__ __forceinline__ ushort_t bf16r(float x) {
    __hip_bfloat16 h = __float2bfloat16(x);
    return *reinterpret_cast<ushort_t*>(&h);
}
__device__ __forceinline__ float bf16tof(ushort_t u) {
    unsigned v = ((unsigned)u) << 16;
    return *reinterpret_cast<float*>(&v);
}
__device__ __forceinline__ unsigned pack2(float a, float b) {
    return ((unsigned)bf16r(b) << 16) | (unsigned)bf16r(a);
}

// ---------------- kernel 0: all weights f32 -> bf16, one launch ----------------
// dst layout (halves): W1b[65536] | W2b[65536] | Wq[4096] | Wk[4096] | Wv[16384] | Wt[16384]
__global__ void k_cvt_all(const float* __restrict__ W1, const float* __restrict__ W2,
                          const float* __restrict__ Wq, const float* __restrict__ Wk,
                          const float* __restrict__ Wv, const float* __restrict__ Wt,
                          ushort_t* __restrict__ dst) {
    int i = blockIdx.x * BDIM + threadIdx.x;     // float4 index, 43008 total
    const float* src; int off;
    if (i < 16384)      { src = W1; off = 0; }
    else if (i < 32768) { src = W2; off = 16384; }
    else if (i < 33792) { src = Wq; off = 32768; }
    else if (i < 34816) { src = Wk; off = 33792; }
    else if (i < 38912) { src = Wv; off = 34816; }
    else                { src = Wt; off = 38912; }
    float4 v = ((const float4*)src)[i - off];
    *(uint2*)(dst + (long)i * 4) = make_uint2(pack2(v.x, v.y), pack2(v.z, v.w));
}

// ---------------- kernel 1: MFMA q/k/vT projection ----------------
__global__ __launch_bounds__(256) void k_proj(
        const float* __restrict__ x, const ushort_t* __restrict__ Wb,
        const float* __restrict__ bv,
        ushort_t* __restrict__ qg, ushort_t* __restrict__ kg,
        ushort_t* __restrict__ vTg) {
    __shared__ ushort_t xs[32][136];
    __shared__ ushort_t qks[32][72];    // q cols 0-31, k cols 32-63
    __shared__ ushort_t vs[32][136];
    long base = (long)blockIdx.x * 32;
    int b = (int)(base >> 11);
    int n0 = (int)(base & (NN - 1));
    int t = threadIdx.x, w = t >> 6, l = t & 63, a = l & 15, g = l >> 4;
    {
        const float4* xg4 = (const float4*)(x + base * CC);
        #pragma unroll
        for (int rep = 0; rep < 4; ++rep) {
            int i = rep * BDIM + t;
            float4 v4 = xg4[i];
            int p = i >> 5, c4 = (i & 31) * 4;
            *(uint2*)&xs[p][c4] = make_uint2(pack2(v4.x, v4.y), pack2(v4.z, v4.w));
        }
    }
    s16x8 bF[3][4];
    #pragma unroll
    for (int ct = 0; ct < 3; ++ct) {
        int ctg = w * 3 + ct;
        #pragma unroll
        for (int ki = 0; ki < 4; ++ki)
            bF[ct][ki] = *(const s16x8*)(Wb + ((long)(ctg * 16 + a)) * CC + ki * 32 + g * 8);
    }
    __syncthreads();
    #pragma unroll
    for (int rt = 0; rt < 2; ++rt) {
        s16x8 aF[4];
        #pragma unroll
        for (int ki = 0; ki < 4; ++ki)
            aF[ki] = *(const s16x8*)&xs[rt * 16 + a][ki * 32 + g * 8];
        #pragma unroll
        for (int ct = 0; ct < 3; ++ct) {
            f32x4 acc = (f32x4){0.f, 0.f, 0.f, 0.f};
            #pragma unroll
            for (int ki = 0; ki < 4; ++ki)
                acc = __builtin_amdgcn_mfma_f32_16x16x32_bf16(aF[ki], bF[ct][ki], acc, 0, 0, 0);
            int ctg = w * 3 + ct;
            int oc = ctg * 16 + a;
            float bias = (oc >= 64) ? bv[oc - 64] : 0.f;
            #pragma unroll
            for (int r = 0; r < 4; ++r) {
                int p = rt * 16 + g * 4 + r;
                float val = acc[r] + bias;
                if (oc < 64) qks[p][oc] = bf16r(val);
                else         vs[p][oc - 64] = bf16r(val);
            }
        }
    }
    __syncthreads();
    {
        int p = t >> 3, c = (t & 7) * 4;
        *(uint2*)(qg + (base + p) * DD + c) = *(const uint2*)&qks[p][c];
        *(uint2*)(kg + (base + p) * DD + c) = *(const uint2*)&qks[p][32 + c];
    }
    #pragma unroll
    for (int rep = 0; rep < 2; ++rep) {
        int i = rep * BDIM + t;
        int c = i & 127, nch = i >> 7;
        int p0 = nch * 8;
        uint4 r;
        r.x = (unsigned)vs[p0+0][c] | ((unsigned)vs[p0+1][c] << 16);
        r.y = (unsigned)vs[p0+2][c] | ((unsigned)vs[p0+3][c] << 16);
        r.z = (unsigned)vs[p0+4][c] | ((unsigned)vs[p0+5][c] << 16);
        r.w = (unsigned)vs[p0+6][c] | ((unsigned)vs[p0+7][c] << 16);
        *(uint4*)(vTg + ((long)(b * CC + c)) * NN + n0 + p0) = r;
    }
}

// ---------------- kernel 2: MFMA row softmax sums, 64 rows/block + kB prefetch ----------------
__global__ __launch_bounds__(256) void k_rowstats(
        const ushort_t* __restrict__ qg, const ushort_t* __restrict__ kg,
        float* __restrict__ rowinv) {
    __shared__ float ps[4][64];
    int b = blockIdx.x >> 5;
    int nt = (blockIdx.x & 31) * 64;
    int t = threadIdx.x, w = t >> 6, l = t & 63, a = l & 15, g = l >> 4;
    s16x8 qA[4];
    #pragma unroll
    for (int s = 0; s < 4; ++s)
        qA[s] = *(const s16x8*)(qg + ((long)(b * NN + nt + s*16 + a)) * DD + g*8);
    float sm[16];
    #pragma unroll
    for (int i = 0; i < 16; ++i) sm[i] = 0.f;
    s16x8 kB = *(const s16x8*)(kg + ((long)(b * NN + w * 16 + a)) * DD + g*8);
    for (int it = 0; it < 32; ++it) {
        s16x8 kBn;
        if (it < 31)
            kBn = *(const s16x8*)(kg + ((long)(b * NN + ((it+1)*4 + w)*16 + a)) * DD + g*8);
        #pragma unroll
        for (int s = 0; s < 4; ++s) {
            f32x4 D = (f32x4){0.f, 0.f, 0.f, 0.f};
            D = __builtin_amdgcn_mfma_f32_16x16x32_bf16(qA[s], kB, D, 0, 0, 0);
            #pragma unroll
            for (int r = 0; r < 4; ++r)
                sm[s * 4 + r] += __expf(D[r] * SCALE);
        }
        kB = kBn;
    }
    #pragma unroll
    for (int off = 1; off < 16; off <<= 1)
        #pragma unroll
        for (int ix = 0; ix < 16; ++ix)
            sm[ix] += __shfl_xor(sm[ix], off, 64);
    if (a == 0) {
        #pragma unroll
        for (int s = 0; s < 4; ++s)
            #pragma unroll
            for (int r = 0; r < 4; ++r)
                ps[w][s * 16 + g * 4 + r] = sm[s * 4 + r];
    }
    __syncthreads();
    if (t < 64) {
        float S = ps[0][t] + ps[1][t] + ps[2][t] + ps[3][t];
        rowinv[(long)b * NN + nt + t] = 1.f / S;
    }
}

// ---------------- kernel 3: MFMA PV + fused tproj epilogue ----------------
// grid: 8 b x 64 m-tiles(32) = 512 blocks x 512 thr.
// epilogue: hb = bf16(x + relu(BN1(Wt (x - xr) + bt))) with xr = acc (in regs).
__global__ __launch_bounds__(512) void k_pv(
        const ushort_t* __restrict__ qg, const ushort_t* __restrict__ kg,
        const ushort_t* __restrict__ vTg, const float* __restrict__ rowinv,
        const float* __restrict__ x, const ushort_t* __restrict__ Wtb,
        const float* __restrict__ bt,
        const float* __restrict__ g1, const float* __restrict__ b1,
        const float* __restrict__ m1, const float* __restrict__ v1,
        ushort_t* __restrict__ hb) {
    __shared__ ushort_t qs[2][64][40];
    __shared__ ushort_t ks[32][40];
    __shared__ ushort_t vTs[2][128][72];
    __shared__ ushort_t pT[32][72];
    __shared__ float rin_s[2][64];
    __shared__ ushort_t xb[32][136];   // epilogue: bf16 x tile
    __shared__ ushort_t ds[32][136];   // epilogue: bf16 (x - xr)
    int b = blockIdx.x >> 6;
    int m0 = (blockIdx.x & 63) * 32;
    int t = threadIdx.x, w = t >> 6, l = t & 63, a = l & 15, g = l >> 4;
    int nsub = w & 3, msub = w >> 2;
    const ushort_t* vTb = vTg + (long)b * CC * NN;
    if (t < 128) {
        int r = t >> 2, o = (t & 3) * 8;
        *(s16x8*)&ks[r][o] = *(const s16x8*)(kg + ((long)(b * NN + m0 + r)) * DD + o);
    }
    int qr = t >> 2, qo = (t & 3) * 8;
    int c0 = t >> 3, vo0 = (t & 7) * 8;
    int c1 = (512 + t) >> 3, vo1 = (t & 7) * 8;
    uint4 qreg = make_uint4(0, 0, 0, 0), vreg0, vreg1;
    float rinreg = 0.f;
    if (t < 256) qreg = *(const uint4*)(qg + ((long)(b * NN + qr)) * DD + qo);
    vreg0 = *(const uint4*)(vTb + (long)c0 * NN + vo0);
    vreg1 = *(const uint4*)(vTb + (long)c1 * NN + vo1);
    if (t < 64) rinreg = rowinv[(long)b * NN + t];
    if (t < 256) *(uint4*)&qs[0][qr][qo] = qreg;
    *(uint4*)&vTs[0][c0][vo0] = vreg0;
    *(uint4*)&vTs[0][c1][vo1] = vreg1;
    if (t < 64) rin_s[0][t] = rinreg;

    f32x4 acc[2];
    acc[0] = (f32x4){0.f, 0.f, 0.f, 0.f};
    acc[1] = (f32x4){0.f, 0.f, 0.f, 0.f};
    int cur = 0;
    for (int it = 0; it < 32; ++it) {
        __syncthreads();
        int ntn = (it + 1) * 64;
        if (it < 31) {
            if (t < 256) qreg = *(const uint4*)(qg + ((long)(b * NN + ntn + qr)) * DD + qo);
            vreg0 = *(const uint4*)(vTb + (long)c0 * NN + ntn + vo0);
            vreg1 = *(const uint4*)(vTb + (long)c1 * NN + ntn + vo1);
            if (t < 64) rinreg = rowinv[(long)b * NN + ntn + t];
        }
        s16x8 qf = *(const s16x8*)&qs[cur][nsub * 16 + a][g * 8];
        s16x8 kf = *(const s16x8*)&ks[msub * 16 + a][g * 8];
        f32x4 e = (f32x4){0.f, 0.f, 0.f, 0.f};
        e = __builtin_amdgcn_mfma_f32_16x16x32_bf16(qf, kf, e, 0, 0, 0);
        float p[4];
        #pragma unroll
        for (int r = 0; r < 4; ++r)
            p[r] = __expf(e[r] * SCALE) * rin_s[cur][nsub * 16 + g * 4 + r];
        *(uint2*)&pT[msub * 16 + a][nsub * 16 + g * 4] =
            make_uint2(pack2(p[0], p[1]), pack2(p[2], p[3]));
        __syncthreads();
        #pragma unroll
        for (int k2 = 0; k2 < 2; ++k2) {
            s16x8 A0 = *(const s16x8*)&pT[a][k2 * 32 + g * 8];
            s16x8 A1 = *(const s16x8*)&pT[16 + a][k2 * 32 + g * 8];
            s16x8 Bf = *(const s16x8*)&vTs[cur][w * 16 + a][k2 * 32 + g * 8];
            acc[0] = __builtin_amdgcn_mfma_f32_16x16x32_bf16(A0, Bf, acc[0], 0, 0, 0);
            acc[1] = __builtin_amdgcn_mfma_f32_16x16x32_bf16(A1, Bf, acc[1], 0, 0, 0);
        }
        if (it < 31) {
            if (t < 256) *(uint4*)&qs[cur ^ 1][qr][qo] = qreg;
            *(uint4*)&vTs[cur ^ 1][c0][vo0] = vreg0;
            *(uint4*)&vTs[cur ^ 1][c1][vo1] = vreg1;
            if (t < 64) rin_s[cur ^ 1][t] = rinreg;
        }
        cur ^= 1;
    }
    // ---------------- fused tproj epilogue ----------------
    long pbase = (long)b * NN + m0;        // 32 points
    {
        const float4* xg4 = (const float4*)(x + pbase * CC);
        #pragma unroll
        for (int rep = 0; rep < 2; ++rep) {
            int i = rep * 512 + t;          // 1024 float4
            float4 xv = xg4[i];
            int p = i >> 5, c4 = (i & 31) * 4;
            *(uint2*)&xb[p][c4] = make_uint2(pack2(xv.x, xv.y), pack2(xv.z, xv.w));
        }
    }
    __syncthreads();
    // d = x - xr : lane (w,a,g) owns c = w*16+a, rows ms*16+g*4+r
    #pragma unroll
    for (int ms = 0; ms < 2; ++ms)
        #pragma unroll
        for (int r = 0; r < 4; ++r) {
            int ml = ms * 16 + g * 4 + r;
            int c = w * 16 + a;
            ds[ml][c] = bf16r(bf16tof(xb[ml][c]) - acc[ms][r]);
        }
    __syncthreads();
    // tproj MFMA: 8 waves -> ph = w&1 (m-half), fh = w>>1 (o-range of 32)
    {
        int ph = w & 1, fh = w >> 1;
        s16x8 aF[4];
        #pragma unroll
        for (int ki = 0; ki < 4; ++ki)
            aF[ki] = *(const s16x8*)&ds[ph * 16 + a][ki * 32 + g * 8];
        #pragma unroll
        for (int oi = 0; oi < 2; ++oi) {
            int ot = fh * 2 + oi;
            f32x4 ac = (f32x4){0.f, 0.f, 0.f, 0.f};
            #pragma unroll
            for (int ki = 0; ki < 4; ++ki) {
                s16x8 bF = *(const s16x8*)(Wtb + ((long)(ot * 16 + a)) * CC + ki * 32 + g * 8);
                ac = __builtin_amdgcn_mfma_f32_16x16x32_bf16(aF[ki], bF, ac, 0, 0, 0);
            }
            int o = ot * 16 + a;
            float sc = g1[o] * rsqrtf(v1[o] + 1e-5f);
            float mm = m1[o], bb = b1[o], bo = bt[o];
            #pragma unroll
            for (int r = 0; r < 4; ++r) {
                int p = ph * 16 + g * 4 + r;
                float tv = ((ac[r] + bo) - mm) * sc + bb;
                tv = fmaxf(tv, 0.f);
                hb[(pbase + p) * CC + o] = bf16r(bf16tof(xb[p][o]) + tv);
            }
        }
    }
}

// ---------------- kernel 5: MFMA fused FF, double-buffered weight chunks ----------------
// XOR-swizzled unpadded weight buffers: lds[row][col ^ ((row&7)*8)] (halves).
__global__ __launch_bounds__(256) void k_ff(
        const ushort_t* __restrict__ hb, const ushort_t* __restrict__ W1b,
        const ushort_t* __restrict__ W2b,
        const float* __restrict__ bf1, const float* __restrict__ bf2,
        const float* __restrict__ g2, const float* __restrict__ b2,
        const float* __restrict__ m2, const float* __restrict__ v2,
        float* __restrict__ out) {
    __shared__ ushort_t hs[32][136];
    __shared__ ushort_t w1s[2][64][128];
    __shared__ ushort_t w2s[2][128][64];
    __shared__ ushort_t fss[32][72];
    long pbase = (long)blockIdx.x * 32;
    int t = threadIdx.x;
    int l = t & 63, wid = t >> 6;
    int ph = wid & 1, fh = wid >> 1;
    int lr = l & 15, lg = l >> 4;
    for (int i = t; i < 512; i += BDIM) {
        int r = i >> 4, c0 = (i & 15) * 8;
        *(uint4*)&hs[r][c0] = *(const uint4*)(hb + (pbase + r) * CC + c0);
    }
    #pragma unroll
    for (int rep = 0; rep < 4; ++rep) {
        int i = rep * BDIM + t;
        int r = i >> 4, c0 = (i & 15) * 8;
        *(uint4*)&w1s[0][r][c0 ^ ((r & 7) * 8)] = *(const uint4*)(W1b + (long)r * CC + c0);
    }
    #pragma unroll
    for (int rep = 0; rep < 4; ++rep) {
        int i = rep * BDIM + t;
        int r = i >> 3, c0 = (i & 7) * 8;
        *(uint4*)&w2s[0][r][c0 ^ ((r & 7) * 8)] = *(const uint4*)(W2b + (long)r * FF + c0);
    }
    __syncthreads();
    s16x8 hA[4];
    #pragma unroll
    for (int ki = 0; ki < 4; ++ki)
        hA[ki] = *(const s16x8*)&hs[ph * 16 + lr][ki * 32 + lg * 8];
    f32x4 acc2[4];
    #pragma unroll
    for (int i = 0; i < 4; ++i) acc2[i] = (f32x4){0.f, 0.f, 0.f, 0.f};

    int cur = 0;
    uint4 wrg0, wrg1, wrg2, wrg3, wrg4, wrg5, wrg6, wrg7;
    for (int fc = 0; fc < 8; ++fc) {
        if (fc) __syncthreads();
        int f0 = fc * 64;
        if (fc < 7) {
            int f0n = f0 + 64;
            int r1 = t >> 4, c1 = (t & 15) * 8;
            int r2 = t >> 3, c2 = (t & 7) * 8;
            wrg0 = *(const uint4*)(W1b + (long)(f0n + r1) * CC + c1);
            wrg1 = *(const uint4*)(W1b + (long)(f0n + 16 + r1) * CC + c1);
            wrg2 = *(const uint4*)(W1b + (long)(f0n + 32 + r1) * CC + c1);
            wrg3 = *(const uint4*)(W1b + (long)(f0n + 48 + r1) * CC + c1);
            wrg4 = *(const uint4*)(W2b + (long)r2 * FF + f0n + c2);
            wrg5 = *(const uint4*)(W2b + (long)(32 + r2) * FF + f0n + c2);
            wrg6 = *(const uint4*)(W2b + (long)(64 + r2) * FF + f0n + c2);
            wrg7 = *(const uint4*)(W2b + (long)(96 + r2) * FF + f0n + c2);
        }
        #pragma unroll
        for (int fi = 0; fi < 2; ++fi) {
            int ft = fh * 2 + fi;
            int row = ft * 16 + lr;
            f32x4 a1 = (f32x4){0.f, 0.f, 0.f, 0.f};
            #pragma unroll
            for (int ki = 0; ki < 4; ++ki) {
                int col = ki * 32 + lg * 8;
                s16x8 bfr = *(const s16x8*)&w1s[cur][row][col ^ ((row & 7) * 8)];
                a1 = __builtin_amdgcn_mfma_f32_16x16x32_bf16(hA[ki], bfr, a1, 0, 0, 0);
            }
            float bias = bf1[f0 + ft * 16 + lr];
            #pragma unroll
            for (int r = 0; r < 4; ++r) {
                float vv = fmaxf(a1[r] + bias, 0.f);
                fss[ph * 16 + lg * 4 + r][ft * 16 + lr] = bf16r(vv);
            }
        }
        __syncthreads();
        #pragma unroll
        for (int k2 = 0; k2 < 2; ++k2) {
            s16x8 afr = *(const s16x8*)&fss[ph * 16 + lr][k2 * 32 + lg * 8];
            #pragma unroll
            for (int oi = 0; oi < 4; ++oi) {
                int ot = fh * 4 + oi;
                int row = ot * 16 + lr;
                int col = k2 * 32 + lg * 8;
                s16x8 bfr = *(const s16x8*)&w2s[cur][row][col ^ ((row & 7) * 8)];
                acc2[oi] = __builtin_amdgcn_mfma_f32_16x16x32_bf16(afr, bfr, acc2[oi], 0, 0, 0);
            }
        }
        if (fc < 7) {
            int nb = cur ^ 1;
            int r1 = t >> 4, c1 = (t & 15) * 8;
            int r2 = t >> 3, c2 = (t & 7) * 8;
            *(uint4*)&w1s[nb][r1][c1 ^ ((r1 & 7) * 8)] = wrg0;
            *(uint4*)&w1s[nb][16 + r1][c1 ^ ((r1 & 7) * 8)] = wrg1;
            *(uint4*)&w1s[nb][32 + r1][c1 ^ ((r1 & 7) * 8)] = wrg2;
            *(uint4*)&w1s[nb][48 + r1][c1 ^ ((r1 & 7) * 8)] = wrg3;
            *(uint4*)&w2s[nb][r2][c2 ^ ((r2 & 7) * 8)] = wrg4;
            *(uint4*)&w2s[nb][32 + r2][c2 ^ (((32 + r2) & 7) * 8)] = wrg5;
            *(uint4*)&w2s[nb][64 + r2][c2 ^ (((64 + r2) & 7) * 8)] = wrg6;
            *(uint4*)&w2s[nb][96 + r2][c2 ^ (((96 + r2) & 7) * 8)] = wrg7;
            cur = nb;
        }
    }
    #pragma unroll
    for (int oi = 0; oi < 4; ++oi) {
        int o = (fh * 4 + oi) * 16 + lr;
        float sc = g2[o] * rsqrtf(v2[o] + 1e-5f);
        float mm = m2[o], bb = b2[o], bias2 = bf2[o];
        #pragma unroll
        for (int r = 0; r < 4; ++r) {
            int p = ph * 16 + lg * 4 + r;
            float val = bf16tof(hs[p][o]) + acc2[oi][r] + bias2;
            out[(pbase + p) * CC + o] = (val - mm) * sc + bb;
        }
    }
}

extern "C" void kernel_launch(void* const* d_in, const int* in_sizes, int n_in,
                              void* d_out, int out_size, void* d_ws, size_t ws_size,
                              hipStream_t stream) {
    const float* x   = (const float*)d_in[0];
    const float* Wq  = (const float*)d_in[1];
    const float* Wk  = (const float*)d_in[2];
    const float* Wv  = (const float*)d_in[3];
    const float* bv  = (const float*)d_in[4];
    const float* Wt  = (const float*)d_in[5];
    const float* bt  = (const float*)d_in[6];
    const float* g1  = (const float*)d_in[7];
    const float* b1  = (const float*)d_in[8];
    const float* m1  = (const float*)d_in[9];
    const float* v1  = (const float*)d_in[10];
    const float* W1  = (const float*)d_in[11];
    const float* bf1 = (const float*)d_in[12];
    const float* W2  = (const float*)d_in[13];
    const float* bf2 = (const float*)d_in[14];
    const float* g2  = (const float*)d_in[15];
    const float* b2  = (const float*)d_in[16];
    const float* m2  = (const float*)d_in[17];
    const float* v2  = (const float*)d_in[18];
    float* out = (float*)d_out;

    float* ws  = (float*)d_ws;
    float* rin = ws;                            // NPTS
    ushort_t* qg   = (ushort_t*)(rin + NPTS);   // NPTS*DD
    ushort_t* kg   = qg + (long)NPTS * DD;      // NPTS*DD
    ushort_t* vTg  = kg + (long)NPTS * DD;      // NPTS*CC ([b][c][n])
    ushort_t* hbuf = vTg + (long)NPTS * CC;     // NPTS*CC
    ushort_t* W1b  = hbuf + (long)NPTS * CC;    // FF*CC
    ushort_t* W2b  = W1b + FF * CC;             // FF*CC
    ushort_t* Wb   = W2b + FF * CC;             // 192*CC (Wq|Wk|Wv)
    ushort_t* Wtb  = Wb + 192 * CC;             // CC*CC

    k_cvt_all<<<168, BDIM, 0, stream>>>(W1, W2, Wq, Wk, Wv, Wt, W1b);
    k_proj<<<NPTS / 32, BDIM, 0, stream>>>(x, Wb, bv, qg, kg, vTg);
    k_rowstats<<<8 * (NN / 64), BDIM, 0, stream>>>(qg, kg, rin);
    k_pv<<<8 * (NN / 32), 512, 0, stream>>>(qg, kg, vTg, rin,
                                            x, Wtb, bt, g1, b1, m1, v1, hbuf);
    k_ff<<<NPTS / 32, BDIM, 0, stream>>>(hbuf, W1b, W2b, bf1, bf2, g2, b2, m2, v2, out);
}

// Round 11
// 78.829 us; speedup vs baseline: 1.2630x; 1.0227x over previous
//
#include <hip/hip_runtime.h>
#include <hip/hip_bf16.h>

#define BDIM 256
#define NPTS (8 * 2048)           // B*N
#define CC 128
#define DD 32
#define FF 512
#define NN 2048
#define SCALE 0.08838834764831845f   // 1/sqrt(128)

typedef float f32x4 __attribute__((ext_vector_type(4)));
typedef short s16x8 __attribute__((ext_vector_type(8)));
typedef unsigned short ushort_t;

__device__ __forceinline__ ushort_t bf16r(float x) {
    __hip_bfloat16 h = __float2bfloat16(x);
    return *reinterpret_cast<ushort_t*>(&h);
}
__device__ __forceinline__ float bf16tof(ushort_t u) {
    unsigned v = ((unsigned)u) << 16;
    return *reinterpret_cast<float*>(&v);
}
__device__ __forceinline__ unsigned pack2(float a, float b) {
    return ((unsigned)bf16r(b) << 16) | (unsigned)bf16r(a);
}

// ---------------- kernel 0: all weights f32 -> bf16, one launch ----------------
__global__ void k_cvt_all(const float* __restrict__ W1, const float* __restrict__ W2,
                          const float* __restrict__ Wq, const float* __restrict__ Wk,
                          const float* __restrict__ Wv, const float* __restrict__ Wt,
                          ushort_t* __restrict__ dst) {
    int i = blockIdx.x * BDIM + threadIdx.x;     // float4 index, 43008 total
    const float* src; int off;
    if (i < 16384)      { src = W1; off = 0; }
    else if (i < 32768) { src = W2; off = 16384; }
    else if (i < 33792) { src = Wq; off = 32768; }
    else if (i < 34816) { src = Wk; off = 33792; }
    else if (i < 38912) { src = Wv; off = 34816; }
    else                { src = Wt; off = 38912; }
    float4 v = ((const float4*)src)[i - off];
    *(uint2*)(dst + (long)i * 4) = make_uint2(pack2(v.x, v.y), pack2(v.z, v.w));
}

// ---------------- kernel 1: MFMA q/k/vT projection ----------------
__global__ __launch_bounds__(256) void k_proj(
        const float* __restrict__ x, const ushort_t* __restrict__ Wb,
        const float* __restrict__ bv,
        ushort_t* __restrict__ qg, ushort_t* __restrict__ kg,
        ushort_t* __restrict__ vTg) {
    __shared__ ushort_t xs[32][136];
    __shared__ ushort_t qks[32][72];    // q cols 0-31, k cols 32-63
    __shared__ ushort_t vs[32][136];
    long base = (long)blockIdx.x * 32;
    int b = (int)(base >> 11);
    int n0 = (int)(base & (NN - 1));
    int t = threadIdx.x, w = t >> 6, l = t & 63, a = l & 15, g = l >> 4;
    {
        const float4* xg4 = (const float4*)(x + base * CC);
        #pragma unroll
        for (int rep = 0; rep < 4; ++rep) {
            int i = rep * BDIM + t;
            float4 v4 = xg4[i];
            int p = i >> 5, c4 = (i & 31) * 4;
            *(uint2*)&xs[p][c4] = make_uint2(pack2(v4.x, v4.y), pack2(v4.z, v4.w));
        }
    }
    s16x8 bF[3][4];
    #pragma unroll
    for (int ct = 0; ct < 3; ++ct) {
        int ctg = w * 3 + ct;
        #pragma unroll
        for (int ki = 0; ki < 4; ++ki)
            bF[ct][ki] = *(const s16x8*)(Wb + ((long)(ctg * 16 + a)) * CC + ki * 32 + g * 8);
    }
    __syncthreads();
    #pragma unroll
    for (int rt = 0; rt < 2; ++rt) {
        s16x8 aF[4];
        #pragma unroll
        for (int ki = 0; ki < 4; ++ki)
            aF[ki] = *(const s16x8*)&xs[rt * 16 + a][ki * 32 + g * 8];
        #pragma unroll
        for (int ct = 0; ct < 3; ++ct) {
            f32x4 acc = (f32x4){0.f, 0.f, 0.f, 0.f};
            #pragma unroll
            for (int ki = 0; ki < 4; ++ki)
                acc = __builtin_amdgcn_mfma_f32_16x16x32_bf16(aF[ki], bF[ct][ki], acc, 0, 0, 0);
            int ctg = w * 3 + ct;
            int oc = ctg * 16 + a;
            float bias = (oc >= 64) ? bv[oc - 64] : 0.f;
            #pragma unroll
            for (int r = 0; r < 4; ++r) {
                int p = rt * 16 + g * 4 + r;
                float val = acc[r] + bias;
                if (oc < 64) qks[p][oc] = bf16r(val);
                else         vs[p][oc - 64] = bf16r(val);
            }
        }
    }
    __syncthreads();
    {
        int p = t >> 3, c = (t & 7) * 4;
        *(uint2*)(qg + (base + p) * DD + c) = *(const uint2*)&qks[p][c];
        *(uint2*)(kg + (base + p) * DD + c) = *(const uint2*)&qks[p][32 + c];
    }
    #pragma unroll
    for (int rep = 0; rep < 2; ++rep) {
        int i = rep * BDIM + t;
        int c = i & 127, nch = i >> 7;
        int p0 = nch * 8;
        uint4 r;
        r.x = (unsigned)vs[p0+0][c] | ((unsigned)vs[p0+1][c] << 16);
        r.y = (unsigned)vs[p0+2][c] | ((unsigned)vs[p0+3][c] << 16);
        r.z = (unsigned)vs[p0+4][c] | ((unsigned)vs[p0+5][c] << 16);
        r.w = (unsigned)vs[p0+6][c] | ((unsigned)vs[p0+7][c] << 16);
        *(uint4*)(vTg + ((long)(b * CC + c)) * NN + n0 + p0) = r;
    }
}

// ---------------- kernel 2: MFMA row softmax sums, 64 rows/block + kB prefetch ----------------
__global__ __launch_bounds__(256) void k_rowstats(
        const ushort_t* __restrict__ qg, const ushort_t* __restrict__ kg,
        float* __restrict__ rowinv) {
    __shared__ float ps[4][64];
    int b = blockIdx.x >> 5;
    int nt = (blockIdx.x & 31) * 64;
    int t = threadIdx.x, w = t >> 6, l = t & 63, a = l & 15, g = l >> 4;
    s16x8 qA[4];
    #pragma unroll
    for (int s = 0; s < 4; ++s)
        qA[s] = *(const s16x8*)(qg + ((long)(b * NN + nt + s*16 + a)) * DD + g*8);
    float sm[16];
    #pragma unroll
    for (int i = 0; i < 16; ++i) sm[i] = 0.f;
    s16x8 kB = *(const s16x8*)(kg + ((long)(b * NN + w * 16 + a)) * DD + g*8);
    for (int it = 0; it < 32; ++it) {
        s16x8 kBn;
        if (it < 31)
            kBn = *(const s16x8*)(kg + ((long)(b * NN + ((it+1)*4 + w)*16 + a)) * DD + g*8);
        #pragma unroll
        for (int s = 0; s < 4; ++s) {
            f32x4 D = (f32x4){0.f, 0.f, 0.f, 0.f};
            D = __builtin_amdgcn_mfma_f32_16x16x32_bf16(qA[s], kB, D, 0, 0, 0);
            #pragma unroll
            for (int r = 0; r < 4; ++r)
                sm[s * 4 + r] += __expf(D[r] * SCALE);
        }
        kB = kBn;
    }
    #pragma unroll
    for (int off = 1; off < 16; off <<= 1)
        #pragma unroll
        for (int ix = 0; ix < 16; ++ix)
            sm[ix] += __shfl_xor(sm[ix], off, 64);
    if (a == 0) {
        #pragma unroll
        for (int s = 0; s < 4; ++s)
            #pragma unroll
            for (int r = 0; r < 4; ++r)
                ps[w][s * 16 + g * 4 + r] = sm[s * 4 + r];
    }
    __syncthreads();
    if (t < 64) {
        float S = ps[0][t] + ps[1][t] + ps[2][t] + ps[3][t];
        rowinv[(long)b * NN + nt + t] = 1.f / S;
    }
}

// ---------------- kernel 3: MFMA PV, 1-barrier pipeline (E_t || PV_{t-1}) + tproj epilogue ----------------
// grid: 8 b x 64 m-tiles(32) = 512 blocks x 512 thr.
// arena layout (bytes): vTs[3][128][72] @0 (55296) | qs[2][64][40] @55296 (10240)
//   | ks[32][40] @65536 (2560) | pT[2][32][72] @68096 (9216) | rin[2][64] @77312 (512)
// epilogue aliases arena[0..17407] as xb[32][136] + dsx[32][136] (after final barrier).
__global__ __launch_bounds__(512) void k_pv(
        const ushort_t* __restrict__ qg, const ushort_t* __restrict__ kg,
        const ushort_t* __restrict__ vTg, const float* __restrict__ rowinv,
        const float* __restrict__ x, const ushort_t* __restrict__ Wtb,
        const float* __restrict__ bt,
        const float* __restrict__ g1, const float* __restrict__ b1,
        const float* __restrict__ m1, const float* __restrict__ v1,
        ushort_t* __restrict__ hb) {
    __shared__ __align__(16) char arena[77824];
    auto vTs   = (ushort_t (*)[128][72])(arena);
    auto qs    = (ushort_t (*)[64][40])(arena + 55296);
    auto ks    = (ushort_t (*)[40])(arena + 65536);
    auto pT    = (ushort_t (*)[32][72])(arena + 68096);
    auto rin_s = (float (*)[64])(arena + 77312);
    int b = blockIdx.x >> 6;
    int m0 = (blockIdx.x & 63) * 32;
    int t = threadIdx.x, w = t >> 6, l = t & 63, a = l & 15, g = l >> 4;
    int nsub = w & 3, msub = w >> 2;
    const ushort_t* vTb = vTg + (long)b * CC * NN;
    if (t < 128) {
        int r = t >> 2, o = (t & 3) * 8;
        *(s16x8*)&ks[r][o] = *(const s16x8*)(kg + ((long)(b * NN + m0 + r)) * DD + o);
    }
    int qr = t >> 2, qo = (t & 3) * 8;
    int c0 = t >> 3, vo0 = (t & 7) * 8;
    int c1 = (512 + t) >> 3, vo1 = (t & 7) * 8;
    uint4 qreg = make_uint4(0, 0, 0, 0), vreg0, vreg1;
    float rinreg = 0.f;
    // prologue: stage tile 0
    if (t < 256) qreg = *(const uint4*)(qg + ((long)(b * NN + qr)) * DD + qo);
    vreg0 = *(const uint4*)(vTb + (long)c0 * NN + vo0);
    vreg1 = *(const uint4*)(vTb + (long)c1 * NN + vo1);
    if (t < 64) rinreg = rowinv[(long)b * NN + t];
    if (t < 256) *(uint4*)&qs[0][qr][qo] = qreg;
    *(uint4*)&vTs[0][c0][vo0] = vreg0;
    *(uint4*)&vTs[0][c1][vo1] = vreg1;
    if (t < 64) rin_s[0][t] = rinreg;
    f32x4 acc[2];
    acc[0] = (f32x4){0.f, 0.f, 0.f, 0.f};
    acc[1] = (f32x4){0.f, 0.f, 0.f, 0.f};
    __syncthreads();
    // pipeline: per phase  E_t (tile it) || PV_{t-1} (tile it-1), ONE barrier
    for (int it = 0; it <= 32; ++it) {
        if (it < 31) {                  // issue tile it+1 global loads
            int ntn = (it + 1) * 64;
            if (t < 256) qreg = *(const uint4*)(qg + ((long)(b * NN + ntn + qr)) * DD + qo);
            vreg0 = *(const uint4*)(vTb + (long)c0 * NN + ntn + vo0);
            vreg1 = *(const uint4*)(vTb + (long)c1 * NN + ntn + vo1);
            if (t < 64) rinreg = rowinv[(long)b * NN + ntn + t];
        }
        if (it < 32) {                  // E phase on tile it -> pT[it&1]
            int bq = it & 1;
            s16x8 qf = *(const s16x8*)&qs[bq][nsub * 16 + a][g * 8];
            s16x8 kf = *(const s16x8*)&ks[msub * 16 + a][g * 8];
            f32x4 e = (f32x4){0.f, 0.f, 0.f, 0.f};
            e = __builtin_amdgcn_mfma_f32_16x16x32_bf16(qf, kf, e, 0, 0, 0);
            float p[4];
            #pragma unroll
            for (int r = 0; r < 4; ++r)
                p[r] = __expf(e[r] * SCALE) * rin_s[bq][nsub * 16 + g * 4 + r];
            *(uint2*)&pT[bq][msub * 16 + a][nsub * 16 + g * 4] =
                make_uint2(pack2(p[0], p[1]), pack2(p[2], p[3]));
        }
        if (it >= 1) {                  // PV phase on tile it-1
            int pb = (it - 1) & 1;
            int vb = (it - 1) % 3;
            #pragma unroll
            for (int k2 = 0; k2 < 2; ++k2) {
                s16x8 A0 = *(const s16x8*)&pT[pb][a][k2 * 32 + g * 8];
                s16x8 A1 = *(const s16x8*)&pT[pb][16 + a][k2 * 32 + g * 8];
                s16x8 Bf = *(const s16x8*)&vTs[vb][w * 16 + a][k2 * 32 + g * 8];
                acc[0] = __builtin_amdgcn_mfma_f32_16x16x32_bf16(A0, Bf, acc[0], 0, 0, 0);
                acc[1] = __builtin_amdgcn_mfma_f32_16x16x32_bf16(A1, Bf, acc[1], 0, 0, 0);
            }
        }
        if (it < 31) {                  // write staged tile it+1
            int bn = (it + 1) & 1;
            int vn = (it + 1) % 3;
            if (t < 256) *(uint4*)&qs[bn][qr][qo] = qreg;
            *(uint4*)&vTs[vn][c0][vo0] = vreg0;
            *(uint4*)&vTs[vn][c1][vo1] = vreg1;
            if (t < 64) rin_s[bn][t] = rinreg;
        }
        __syncthreads();
    }
    // ---------------- fused tproj epilogue (aliases arena) ----------------
    auto xb  = (ushort_t (*)[136])(arena);
    auto dsx = (ushort_t (*)[136])(arena + 8704);
    long pbase = (long)b * NN + m0;        // 32 points
    {
        const float4* xg4 = (const float4*)(x + pbase * CC);
        #pragma unroll
        for (int rep = 0; rep < 2; ++rep) {
            int i = rep * 512 + t;          // 1024 float4
            float4 xv = xg4[i];
            int p = i >> 5, c4 = (i & 31) * 4;
            *(uint2*)&xb[p][c4] = make_uint2(pack2(xv.x, xv.y), pack2(xv.z, xv.w));
        }
    }
    __syncthreads();
    #pragma unroll
    for (int ms = 0; ms < 2; ++ms)
        #pragma unroll
        for (int r = 0; r < 4; ++r) {
            int ml = ms * 16 + g * 4 + r;
            int c = w * 16 + a;
            dsx[ml][c] = bf16r(bf16tof(xb[ml][c]) - acc[ms][r]);
        }
    __syncthreads();
    {
        int ph = w & 1, fh = w >> 1;
        s16x8 aF[4];
        #pragma unroll
        for (int ki = 0; ki < 4; ++ki)
            aF[ki] = *(const s16x8*)&dsx[ph * 16 + a][ki * 32 + g * 8];
        #pragma unroll
        for (int oi = 0; oi < 2; ++oi) {
            int ot = fh * 2 + oi;
            f32x4 ac = (f32x4){0.f, 0.f, 0.f, 0.f};
            #pragma unroll
            for (int ki = 0; ki < 4; ++ki) {
                s16x8 bF = *(const s16x8*)(Wtb + ((long)(ot * 16 + a)) * CC + ki * 32 + g * 8);
                ac = __builtin_amdgcn_mfma_f32_16x16x32_bf16(aF[ki], bF, ac, 0, 0, 0);
            }
            int o = ot * 16 + a;
            float sc = g1[o] * rsqrtf(v1[o] + 1e-5f);
            float mm = m1[o], bb = b1[o], bo = bt[o];
            #pragma unroll
            for (int r = 0; r < 4; ++r) {
                int p = ph * 16 + g * 4 + r;
                float tv = ((ac[r] + bo) - mm) * sc + bb;
                tv = fmaxf(tv, 0.f);
                hb[(pbase + p) * CC + o] = bf16r(bf16tof(xb[p][o]) + tv);
            }
        }
    }
}

// ---------------- kernel 5: MFMA fused FF, double-buffered weight chunks ----------------
__global__ __launch_bounds__(256) void k_ff(
        const ushort_t* __restrict__ hb, const ushort_t* __restrict__ W1b,
        const ushort_t* __restrict__ W2b,
        const float* __restrict__ bf1, const float* __restrict__ bf2,
        const float* __restrict__ g2, const float* __restrict__ b2,
        const float* __restrict__ m2, const float* __restrict__ v2,
        float* __restrict__ out) {
    __shared__ ushort_t hs[32][136];
    __shared__ ushort_t w1s[2][64][128];
    __shared__ ushort_t w2s[2][128][64];
    __shared__ ushort_t fss[32][72];
    long pbase = (long)blockIdx.x * 32;
    int t = threadIdx.x;
    int l = t & 63, wid = t >> 6;
    int ph = wid & 1, fh = wid >> 1;
    int lr = l & 15, lg = l >> 4;
    for (int i = t; i < 512; i += BDIM) {
        int r = i >> 4, c0 = (i & 15) * 8;
        *(uint4*)&hs[r][c0] = *(const uint4*)(hb + (pbase + r) * CC + c0);
    }
    #pragma unroll
    for (int rep = 0; rep < 4; ++rep) {
        int i = rep * BDIM + t;
        int r = i >> 4, c0 = (i & 15) * 8;
        *(uint4*)&w1s[0][r][c0 ^ ((r & 7) * 8)] = *(const uint4*)(W1b + (long)r * CC + c0);
    }
    #pragma unroll
    for (int rep = 0; rep < 4; ++rep) {
        int i = rep * BDIM + t;
        int r = i >> 3, c0 = (i & 7) * 8;
        *(uint4*)&w2s[0][r][c0 ^ ((r & 7) * 8)] = *(const uint4*)(W2b + (long)r * FF + c0);
    }
    __syncthreads();
    s16x8 hA[4];
    #pragma unroll
    for (int ki = 0; ki < 4; ++ki)
        hA[ki] = *(const s16x8*)&hs[ph * 16 + lr][ki * 32 + lg * 8];
    f32x4 acc2[4];
    #pragma unroll
    for (int i = 0; i < 4; ++i) acc2[i] = (f32x4){0.f, 0.f, 0.f, 0.f};

    int cur = 0;
    uint4 wrg0, wrg1, wrg2, wrg3, wrg4, wrg5, wrg6, wrg7;
    for (int fc = 0; fc < 8; ++fc) {
        if (fc) __syncthreads();
        int f0 = fc * 64;
        if (fc < 7) {
            int f0n = f0 + 64;
            int r1 = t >> 4, c1 = (t & 15) * 8;
            int r2 = t >> 3, c2 = (t & 7) * 8;
            wrg0 = *(const uint4*)(W1b + (long)(f0n + r1) * CC + c1);
            wrg1 = *(const uint4*)(W1b + (long)(f0n + 16 + r1) * CC + c1);
            wrg2 = *(const uint4*)(W1b + (long)(f0n + 32 + r1) * CC + c1);
            wrg3 = *(const uint4*)(W1b + (long)(f0n + 48 + r1) * CC + c1);
            wrg4 = *(const uint4*)(W2b + (long)r2 * FF + f0n + c2);
            wrg5 = *(const uint4*)(W2b + (long)(32 + r2) * FF + f0n + c2);
            wrg6 = *(const uint4*)(W2b + (long)(64 + r2) * FF + f0n + c2);
            wrg7 = *(const uint4*)(W2b + (long)(96 + r2) * FF + f0n + c2);
        }
        #pragma unroll
        for (int fi = 0; fi < 2; ++fi) {
            int ft = fh * 2 + fi;
            int row = ft * 16 + lr;
            f32x4 a1 = (f32x4){0.f, 0.f, 0.f, 0.f};
            #pragma unroll
            for (int ki = 0; ki < 4; ++ki) {
                int col = ki * 32 + lg * 8;
                s16x8 bfr = *(const s16x8*)&w1s[cur][row][col ^ ((row & 7) * 8)];
                a1 = __builtin_amdgcn_mfma_f32_16x16x32_bf16(hA[ki], bfr, a1, 0, 0, 0);
            }
            float bias = bf1[f0 + ft * 16 + lr];
            #pragma unroll
            for (int r = 0; r < 4; ++r) {
                float vv = fmaxf(a1[r] + bias, 0.f);
                fss[ph * 16 + lg * 4 + r][ft * 16 + lr] = bf16r(vv);
            }
        }
        __syncthreads();
        #pragma unroll
        for (int k2 = 0; k2 < 2; ++k2) {
            s16x8 afr = *(const s16x8*)&fss[ph * 16 + lr][k2 * 32 + lg * 8];
            #pragma unroll
            for (int oi = 0; oi < 4; ++oi) {
                int ot = fh * 4 + oi;
                int row = ot * 16 + lr;
                int col = k2 * 32 + lg * 8;
                s16x8 bfr = *(const s16x8*)&w2s[cur][row][col ^ ((row & 7) * 8)];
                acc2[oi] = __builtin_amdgcn_mfma_f32_16x16x32_bf16(afr, bfr, acc2[oi], 0, 0, 0);
            }
        }
        if (fc < 7) {
            int nb = cur ^ 1;
            int r1 = t >> 4, c1 = (t & 15) * 8;
            int r2 = t >> 3, c2 = (t & 7) * 8;
            *(uint4*)&w1s[nb][r1][c1 ^ ((r1 & 7) * 8)] = wrg0;
            *(uint4*)&w1s[nb][16 + r1][c1 ^ ((r1 & 7) * 8)] = wrg1;
            *(uint4*)&w1s[nb][32 + r1][c1 ^ ((r1 & 7) * 8)] = wrg2;
            *(uint4*)&w1s[nb][48 + r1][c1 ^ ((r1 & 7) * 8)] = wrg3;
            *(uint4*)&w2s[nb][r2][c2 ^ ((r2 & 7) * 8)] = wrg4;
            *(uint4*)&w2s[nb][32 + r2][c2 ^ (((32 + r2) & 7) * 8)] = wrg5;
            *(uint4*)&w2s[nb][64 + r2][c2 ^ (((64 + r2) & 7) * 8)] = wrg6;
            *(uint4*)&w2s[nb][96 + r2][c2 ^ (((96 + r2) & 7) * 8)] = wrg7;
            cur = nb;
        }
    }
    #pragma unroll
    for (int oi = 0; oi < 4; ++oi) {
        int o = (fh * 4 + oi) * 16 + lr;
        float sc = g2[o] * rsqrtf(v2[o] + 1e-5f);
        float mm = m2[o], bb = b2[o], bias2 = bf2[o];
        #pragma unroll
        for (int r = 0; r < 4; ++r) {
            int p = ph * 16 + lg * 4 + r;
            float val = bf16tof(hs[p][o]) + acc2[oi][r] + bias2;
            out[(pbase + p) * CC + o] = (val - mm) * sc + bb;
        }
    }
}

extern "C" void kernel_launch(void* const* d_in, const int* in_sizes, int n_in,
                              void* d_out, int out_size, void* d_ws, size_t ws_size,
                              hipStream_t stream) {
    const float* x   = (const float*)d_in[0];
    const float* Wq  = (const float*)d_in[1];
    const float* Wk  = (const float*)d_in[2];
    const float* Wv  = (const float*)d_in[3];
    const float* bv  = (const float*)d_in[4];
    const float* Wt  = (const float*)d_in[5];
    const float* bt  = (const float*)d_in[6];
    const float* g1  = (const float*)d_in[7];
    const float* b1  = (const float*)d_in[8];
    const float* m1  = (const float*)d_in[9];
    const float* v1  = (const float*)d_in[10];
    const float* W1  = (const float*)d_in[11];
    const float* bf1 = (const float*)d_in[12];
    const float* W2  = (const float*)d_in[13];
    const float* bf2 = (const float*)d_in[14];
    const float* g2  = (const float*)d_in[15];
    const float* b2  = (const float*)d_in[16];
    const float* m2  = (const float*)d_in[17];
    const float* v2  = (const float*)d_in[18];
    float* out = (float*)d_out;

    float* ws  = (float*)d_ws;
    float* rin = ws;                            // NPTS
    ushort_t* qg   = (ushort_t*)(rin + NPTS);   // NPTS*DD
    ushort_t* kg   = qg + (long)NPTS * DD;      // NPTS*DD
    ushort_t* vTg  = kg + (long)NPTS * DD;      // NPTS*CC ([b][c][n])
    ushort_t* hbuf = vTg + (long)NPTS * CC;     // NPTS*CC
    ushort_t* W1b  = hbuf + (long)NPTS * CC;    // FF*CC
    ushort_t* W2b  = W1b + FF * CC;             // FF*CC
    ushort_t* Wb   = W2b + FF * CC;             // 192*CC (Wq|Wk|Wv)
    ushort_t* Wtb  = Wb + 192 * CC;             // CC*CC

    k_cvt_all<<<168, BDIM, 0, stream>>>(W1, W2, Wq, Wk, Wv, Wt, W1b);
    k_proj<<<NPTS / 32, BDIM, 0, stream>>>(x, Wb, bv, qg, kg, vTg);
    k_rowstats<<<8 * (NN / 64), BDIM, 0, stream>>>(qg, kg, rin);
    k_pv<<<8 * (NN / 32), 512, 0, stream>>>(qg, kg, vTg, rin,
                                            x, Wtb, bt, g1, b1, m1, v1, hbuf);
    k_ff<<<NPTS / 32, BDIM, 0, stream>>>(hbuf, W1b, W2b, bf1, bf2, g2, b2, m2, v2, out);
}